// Round 1
// baseline (49362.268 us; speedup 1.0000x reference)
//
#include <hip/hip_runtime.h>

#define B_   128
#define T_   512
#define IN_  512
#define H_   512
#define NBLK 256
#define NTHR 256

typedef float4 f4;

// ---------- staging helpers (reg-staged global -> LDS, XOR quad swizzle) ----------
__device__ __forceinline__ void stage_load(const float* __restrict__ src, size_t stride,
                                           int col0, f4* sreg, int tid) {
#pragma unroll
  for (int i = 0; i < 8; ++i) {
    int idx = i * 256 + tid;          // 0..2047
    int row = idx >> 4;               // 0..127
    int q   = idx & 15;               // quad within 64-float chunk
    sreg[i] = *(const f4*)(src + (size_t)row * stride + col0 + q * 4);
  }
}

__device__ __forceinline__ void stage_write(f4* buf, const f4* sreg, int tid) {
#pragma unroll
  for (int i = 0; i < 8; ++i) {
    int idx = i * 256 + tid;
    int row = idx >> 4;
    int q   = idx & 15;
    int qs  = q ^ ((row >> 1) & 7);   // bank-conflict-free swizzle
    buf[row * 16 + qs] = sreg[i];
  }
}

// ---------- 16-quad (64-k) FMA over one chunk ----------
__device__ __forceinline__ void fma16(const f4* __restrict__ rb, int r0, int sw,
                                      const float* __restrict__ wr,
                                      const float* __restrict__ wz,
                                      const float* __restrict__ wn,
                                      float& ar0, float& az0, float& an0,
                                      float& ar1, float& az1, float& an1) {
#pragma unroll
  for (int kq = 0; kq < 16; ++kq) {
    const int qs = kq ^ sw;
    const f4 a0 = rb[r0 * 16 + qs];
    const f4 a1 = rb[(r0 + 1) * 16 + qs];
    const f4 vr = *(const f4*)(wr + kq * 4);
    const f4 vz = *(const f4*)(wz + kq * 4);
    const f4 vn = *(const f4*)(wn + kq * 4);
    ar0 = fmaf(a0.x, vr.x, ar0); az0 = fmaf(a0.x, vz.x, az0); an0 = fmaf(a0.x, vn.x, an0);
    ar1 = fmaf(a1.x, vr.x, ar1); az1 = fmaf(a1.x, vz.x, az1); an1 = fmaf(a1.x, vn.x, an1);
    ar0 = fmaf(a0.y, vr.y, ar0); az0 = fmaf(a0.y, vz.y, az0); an0 = fmaf(a0.y, vn.y, an0);
    ar1 = fmaf(a1.y, vr.y, ar1); az1 = fmaf(a1.y, vz.y, az1); an1 = fmaf(a1.y, vn.y, an1);
    ar0 = fmaf(a0.z, vr.z, ar0); az0 = fmaf(a0.z, vz.z, az0); an0 = fmaf(a0.z, vn.z, an0);
    ar1 = fmaf(a1.z, vr.z, ar1); az1 = fmaf(a1.z, vz.z, az1); an1 = fmaf(a1.z, vn.z, an1);
    ar0 = fmaf(a0.w, vr.w, ar0); az0 = fmaf(a0.w, vz.w, az0); an0 = fmaf(a0.w, vn.w, an0);
    ar1 = fmaf(a1.w, vr.w, ar1); az1 = fmaf(a1.w, vz.w, az1); an1 = fmaf(a1.w, vn.w, an1);
  }
}

__device__ __forceinline__ float gru_h(float ar, float az, float anx, float anh,
                                       float brc, float bzc, float bxn, float bhn,
                                       float hold) {
  float r = 1.f / (1.f + __expf(-(ar + brc)));
  float z = 1.f / (1.f + __expf(-(az + bzc)));
  float nv = anx + bxn + r * (anh + bhn);
  nv = fminf(fmaxf(nv, -15.f), 15.f);
  float e = __expf(2.f * nv);
  float n = (e - 1.f) / (e + 1.f);
  return (1.f - z) * n + z * hold;
}

// ---------- persistent 2-layer GRU ----------
__global__ __launch_bounds__(NTHR, 1) void gru_persistent(
    const float* __restrict__ x,
    const float* __restrict__ Wih0, const float* __restrict__ Whh0,
    const float* __restrict__ bih0, const float* __restrict__ bhh0,
    const float* __restrict__ Wih1, const float* __restrict__ Whh1,
    const float* __restrict__ bih1, const float* __restrict__ bhh1,
    unsigned* counter, float* Hbase) {
  __shared__ f4 Abuf[2][2048];      // 2 x 128 rows x 16 quads = 64 KiB

  const int tid  = threadIdx.x;
  const int rg   = tid & 63;
  const int jg   = __builtin_amdgcn_readfirstlane(tid >> 6);  // wave-uniform
  const int bx   = blockIdx.x;
  const int cell = bx >> 7;                 // 0: layer0, 1: layer1
  const int j    = ((bx & 127) << 2) | jg;  // 0..511
  const int r0   = rg << 1;                 // rows r0, r0+1
  const int sw   = rg & 7;

  const float* Wih = cell ? Wih1 : Wih0;
  const float* Whh = cell ? Whh1 : Whh0;
  const float* bih = cell ? bih1 : bih0;
  const float* bhh = cell ? bhh1 : bhh0;
  const float* wxr = Wih + (size_t)j * IN_;
  const float* wxz = Wih + (size_t)(j + H_) * IN_;
  const float* wxn = Wih + (size_t)(j + 2 * H_) * IN_;
  const float* whr = Whh + (size_t)j * H_;
  const float* whz = Whh + (size_t)(j + H_) * H_;
  const float* whn = Whh + (size_t)(j + 2 * H_) * H_;
  const float brc = bih[j] + bhh[j];
  const float bzc = bih[j + H_] + bhh[j + H_];
  const float bxn = bih[j + 2 * H_];
  const float bhn = bhh[j + 2 * H_];

  float* const H1a = Hbase;            // h1 slot 0
  float* const H1b = Hbase + 65536;    // h1 slot 1
  float* const H2a = Hbase + 131072;   // h2 slot 0
  float* const H2b = Hbase + 196608;   // h2 slot 1

  unsigned tgt = 0;
  for (int p = 0; p <= T_; ++p) {
    const int pv = p & 1;
    float* const H1prev = pv ? H1b : H1a;
    float* const H1cur  = pv ? H1a : H1b;
    float* const H2prev = pv ? H2b : H2a;
    float* const H2cur  = pv ? H2a : H2b;
    const bool act = cell ? (p >= 1) : (p < T_);

    if (act) {
      const float* Ax; size_t axs; const float* Ah; const float* Hold; float* Hout;
      if (cell == 0) { Ax = x + (size_t)p * IN_; axs = (size_t)T_ * IN_;
                       Ah = H1prev; Hold = H1prev; Hout = H1cur; }
      else           { Ax = H1prev; axs = H_;
                       Ah = H2prev; Hold = H2prev; Hout = H2cur; }

      float ar0 = 0, az0 = 0, anx0 = 0, anh0 = 0;
      float ar1 = 0, az1 = 0, anx1 = 0, anh1 = 0;
      f4 sreg[8];

      stage_load(Ax, axs, 0, sreg, tid);
      stage_write(&Abuf[0][0], sreg, tid);
      __syncthreads();

      // half 0: k in [0,512) -> x-side, accumulate (r, z, xn)
#pragma unroll 1
      for (int c = 0; c < 8; ++c) {
        if (c < 7) stage_load(Ax, axs, (c + 1) << 6, sreg, tid);
        else       stage_load(Ah, H_, 0, sreg, tid);
        fma16(&Abuf[c & 1][0], r0, sw,
              wxr + (c << 6), wxz + (c << 6), wxn + (c << 6),
              ar0, az0, anx0, ar1, az1, anx1);
        stage_write(&Abuf[(c + 1) & 1][0], sreg, tid);
        __syncthreads();
      }
      // half 1: k in [512,1024) -> h-side, accumulate (r, z, hn)
#pragma unroll 1
      for (int c = 8; c < 16; ++c) {
        if (c < 15) stage_load(Ah, H_, (c - 7) << 6, sreg, tid);
        const int cc = (c - 8) << 6;
        fma16(&Abuf[c & 1][0], r0, sw,
              whr + cc, whz + cc, whn + cc,
              ar0, az0, anh0, ar1, az1, anh1);
        if (c < 15) stage_write(&Abuf[(c + 1) & 1][0], sreg, tid);
        __syncthreads();
      }

      // combine gates + write new h
      {
        size_t i0 = (size_t)r0 * H_ + j;
        size_t i1 = i0 + H_;
        float h0 = Hold[i0], h1v = Hold[i1];
        Hout[i0] = gru_h(ar0, az0, anx0, anh0, brc, bzc, bxn, bhn, h0);
        Hout[i1] = gru_h(ar1, az1, anx1, anh1, brc, bzc, bxn, bhn, h1v);
      }
    }

    // -------- grid barrier (release/acquire, device scope) --------
    tgt += NBLK;
    __syncthreads();
    if (tid == 0) {
      __hip_atomic_fetch_add(counter, 1u, __ATOMIC_RELEASE, __HIP_MEMORY_SCOPE_AGENT);
      while (__hip_atomic_load(counter, __ATOMIC_RELAXED, __HIP_MEMORY_SCOPE_AGENT) < tgt)
        __builtin_amdgcn_s_sleep(2);
      __threadfence();  // acquire side: invalidate so new h-state is visible
    }
    __syncthreads();
  }
}

// ---------- epilogue: out = h2_last @ Wfc^T + bfc ----------
__global__ __launch_bounds__(256) void fc_kernel(const float* __restrict__ h2,
                                                 const float* __restrict__ Wfc,
                                                 const float* __restrict__ bfc,
                                                 float* __restrict__ out) {
  int gid = blockIdx.x * 256 + threadIdx.x;  // 0..16383
  int b = gid >> 7, o = gid & 127;
  const float* hp = h2 + (size_t)b * H_;
  const float* wp = Wfc + (size_t)o * H_;
  float acc = bfc[o];
#pragma unroll 8
  for (int k = 0; k < H_; k += 4) {
    f4 h = *(const f4*)(hp + k);
    f4 w = *(const f4*)(wp + k);
    acc = fmaf(h.x, w.x, acc); acc = fmaf(h.y, w.y, acc);
    acc = fmaf(h.z, w.z, acc); acc = fmaf(h.w, w.w, acc);
  }
  out[gid] = acc;
}

// ---------- epilogue: out_cate = out @ Wfcc^T + bfcc ----------
__global__ __launch_bounds__(256) void fcc_kernel(const float* __restrict__ outv,
                                                  const float* __restrict__ Wfcc,
                                                  const float* __restrict__ bfcc,
                                                  float* __restrict__ oc) {
  int gid = blockIdx.x * 256 + threadIdx.x;  // 0..49151
  int b = gid / 384, g = gid - b * 384;
  const float* op = outv + (size_t)b * 128;
  const float* wp = Wfcc + (size_t)g * 128;
  float acc = bfcc[g];
#pragma unroll 8
  for (int k = 0; k < 128; k += 4) {
    f4 o4 = *(const f4*)(op + k);
    f4 w4 = *(const f4*)(wp + k);
    acc = fmaf(o4.x, w4.x, acc); acc = fmaf(o4.y, w4.y, acc);
    acc = fmaf(o4.z, w4.z, acc); acc = fmaf(o4.w, w4.w, acc);
  }
  oc[gid] = acc;
}

extern "C" void kernel_launch(void* const* d_in, const int* in_sizes, int n_in,
                              void* d_out, int out_size, void* d_ws, size_t ws_size,
                              hipStream_t stream) {
  (void)in_sizes; (void)n_in; (void)out_size; (void)ws_size;
  const float* x    = (const float*)d_in[0];
  const float* Wih0 = (const float*)d_in[1];
  const float* Whh0 = (const float*)d_in[2];
  const float* bih0 = (const float*)d_in[3];
  const float* bhh0 = (const float*)d_in[4];
  const float* Wih1 = (const float*)d_in[5];
  const float* Whh1 = (const float*)d_in[6];
  const float* bih1 = (const float*)d_in[7];
  const float* bhh1 = (const float*)d_in[8];
  const float* Wfc  = (const float*)d_in[9];
  const float* bfc  = (const float*)d_in[10];
  const float* Wfcc = (const float*)d_in[11];
  const float* bfcc = (const float*)d_in[12];

  unsigned* counter = (unsigned*)d_ws;
  float* Hbase = (float*)((char*)d_ws + 256);

  // zero barrier counter + all 4 h-state slots (deterministic per launch)
  hipMemsetAsync(d_ws, 0, 256 + 4 * 262144, stream);

  void* args[] = { (void*)&x,
                   (void*)&Wih0, (void*)&Whh0, (void*)&bih0, (void*)&bhh0,
                   (void*)&Wih1, (void*)&Whh1, (void*)&bih1, (void*)&bhh1,
                   (void*)&counter, (void*)&Hbase };
  hipLaunchCooperativeKernel((void*)gru_persistent, dim3(NBLK), dim3(NTHR),
                             args, 0, stream);

  float* out = (float*)d_out;
  const float* h2fin = Hbase + 196608;  // H2 slot 1 = h2[T-1]
  fc_kernel<<<64, 256, 0, stream>>>(h2fin, Wfc, bfc, out);
  fcc_kernel<<<192, 256, 0, stream>>>(out, Wfcc, bfcc, out + 16384);
}

// Round 3
// 10841.990 us; speedup vs baseline: 4.5529x; 4.5529x over previous
//
#include <hip/hip_runtime.h>

#define Tn 512
#define Hn 512
#define HP 65536           // h elements per parity buffer (128*512)
#define NBLK 256
#define NPH 513

typedef __attribute__((ext_vector_type(8))) short s8v;     // 8 bf16 (MFMA A/B frag)
typedef __attribute__((ext_vector_type(4))) float f4v;     // MFMA acc
typedef __attribute__((ext_vector_type(4))) unsigned u4v;

__device__ __forceinline__ unsigned short f2bf(float f) {  // RNE
  unsigned u = __float_as_uint(f);
  u = u + 0x7fffu + ((u >> 16) & 1u);
  return (unsigned short)(u >> 16);
}
__device__ __forceinline__ float bf2f(unsigned short s) {
  return __uint_as_float(((unsigned)s) << 16);
}
__device__ __forceinline__ float sigm(float v) { return 1.f / (1.f + __expf(-v)); }
__device__ __forceinline__ float tanh_f(float v) {
  v = fminf(fmaxf(v, -15.f), 15.f);
  float e = __expf(2.f * v);
  return (e - 1.f) / (e + 1.f);
}
__device__ __forceinline__ f4v mfma3(s8v ah, s8v al, s8v wh, s8v wl, f4v c) {
  c = __builtin_amdgcn_mfma_f32_16x16x32_bf16(ah, wh, c, 0, 0, 0);
  c = __builtin_amdgcn_mfma_f32_16x16x32_bf16(al, wh, c, 0, 0, 0);
  c = __builtin_amdgcn_mfma_f32_16x16x32_bf16(ah, wl, c, 0, 0, 0);
  return c;
}

// ---------------- persistent fused 2-layer GRU ----------------
// 256 blocks: layer = bid&1, jg = (bid>>1)&31 (16 cols), mhalf = bid>>6 (32 rows).
// 4 waves/block: kh = wv&1 (K-half), hside = wv>>1 (0: x-input GEMM, 1: h GEMM).
// Weights: bf16 hi/lo fragments in VGPRs (48/wave = 192 VGPR), loaded once.
// Phase p: layer0 computes h1[p] (p<512); layer1 computes h2[p-1] (p>=1).
__global__ __launch_bounds__(256, 1) void gru_fused(
    const float* __restrict__ x,
    const float* __restrict__ Wih0, const float* __restrict__ Whh0,
    const float* __restrict__ bih0, const float* __restrict__ bhh0,
    const float* __restrict__ Wih1, const float* __restrict__ Whh1,
    const float* __restrict__ bih1, const float* __restrict__ bhh1,
    unsigned* __restrict__ counter,
    unsigned short* __restrict__ h1hi, unsigned short* __restrict__ h1lo,
    unsigned short* __restrict__ h2hi, unsigned short* __restrict__ h2lo,
    float* __restrict__ h2fin) {
  __shared__ float part[3][64][25];   // partial-acc handoff (stride 25: conflict-free)

  const int tid = threadIdx.x, lane = tid & 63, wv = tid >> 6;
  const int kh = wv & 1, hside = wv >> 1;
  const int colr = lane & 15, kg = lane >> 4;

  const int bid = blockIdx.x;
  const int layer = bid & 1;
  const int jg = (bid >> 1) & 31;
  const int mhalf = bid >> 6;
  const int col = jg * 16 + colr;

  // ---- load weight fragments (this wave's matrix + K-half) ----
  // B-frag: lane holds W[col][k = kh*256 + ks*32 + kg*8 + e]
  const float* W = (layer == 0) ? (hside ? Whh0 : Wih0) : (hside ? Whh1 : Wih1);
  s8v wh[3][8], wl[3][8];
#pragma unroll
  for (int g = 0; g < 3; ++g) {
    const float* wrow = W + (size_t)(g * Hn + col) * Hn + kh * 256 + kg * 8;
#pragma unroll
    for (int ks = 0; ks < 8; ++ks) {
#pragma unroll
      for (int e = 0; e < 8; ++e) {
        float v = wrow[ks * 32 + e];
        unsigned short hi = f2bf(v);
        wh[g][ks][e] = (short)hi;
        wl[g][ks][e] = (short)f2bf(v - bf2f(hi));
      }
    }
  }

  // biases: only the epilogue wave (hside==1, kh==0)
  float brz = 0, bzz = 0, bin = 0, bhn = 0;
  if (hside == 1 && kh == 0) {
    const float* bi = layer ? bih1 : bih0;
    const float* bb = layer ? bhh1 : bhh0;
    brz = bi[col] + bb[col];
    bzz = bi[Hn + col] + bb[Hn + col];
    bin = bi[2 * Hn + col];
    bhn = bb[2 * Hn + col];
  }

  float hown[2][4] = {{0.f, 0.f, 0.f, 0.f}, {0.f, 0.f, 0.f, 0.f}};

  unsigned tgt = 0;
  for (int p = 0; p < NPH; ++p) {
    const bool act = (layer == 0) ? (p < Tn) : (p >= 1);
    const int t = (layer == 0) ? p : (p - 1);   // this block computes h[t]
    f4v acc[2][3];

    if (act) {
#pragma unroll
      for (int mt = 0; mt < 2; ++mt)
#pragma unroll
        for (int g = 0; g < 3; ++g) acc[mt][g] = (f4v){0.f, 0.f, 0.f, 0.f};

      if (layer == 0 && hside == 0) {
        // ---- x-input GEMM: load x fp32, split hi/lo by truncation ----
#pragma unroll
        for (int mt = 0; mt < 2; ++mt) {
          const int rowA = (mhalf * 2 + mt) * 16 + colr;
          const float* xp = x + ((size_t)rowA * Tn + t) * 512 + kh * 256 + kg * 8;
#pragma unroll
          for (int ks = 0; ks < 8; ++ks) {
            float v[8];
#pragma unroll
            for (int e = 0; e < 8; ++e) v[e] = xp[ks * 32 + e];
            u4v au, lu;
#pragma unroll
            for (int q = 0; q < 4; ++q) {
              unsigned u0 = __float_as_uint(v[2 * q]);
              unsigned u1 = __float_as_uint(v[2 * q + 1]);
              unsigned m0 = u0 & 0xffff0000u, m1 = u1 & 0xffff0000u;
              au[q] = (u0 >> 16) | m1;
              float l0 = v[2 * q] - __uint_as_float(m0);
              float l1 = v[2 * q + 1] - __uint_as_float(m1);
              lu[q] = (__float_as_uint(l0) >> 16) | (__float_as_uint(l1) & 0xffff0000u);
            }
            s8v ah = __builtin_bit_cast(s8v, au);
            s8v al = __builtin_bit_cast(s8v, lu);
#pragma unroll
            for (int g = 0; g < 3; ++g)
              acc[mt][g] = mfma3(ah, al, wh[g][ks], wl[g][ks], acc[mt][g]);
          }
        }
      } else {
        // ---- h GEMM: read published bf16 hi/lo state ----
        const unsigned short *sh, *sl;
        int rp;
        if (layer == 0)      { sh = h1hi; sl = h1lo; rp = (t - 1) & 1; }  // h1[t-1]
        else if (hside == 0) { sh = h1hi; sl = h1lo; rp = t & 1; }        // h1[t]
        else                 { sh = h2hi; sl = h2lo; rp = (t - 1) & 1; }  // h2[t-1]
#pragma unroll
        for (int mt = 0; mt < 2; ++mt) {
          const int rowA = (mhalf * 2 + mt) * 16 + colr;
          const size_t base = (size_t)rp * HP + (size_t)rowA * 512 + kh * 256 + kg * 8;
          const unsigned short* ph = sh + base;
          const unsigned short* pl = sl + base;
#pragma unroll
          for (int ks = 0; ks < 8; ++ks) {
            s8v ah = *(const s8v*)(ph + ks * 32);
            s8v al = *(const s8v*)(pl + ks * 32);
#pragma unroll
            for (int g = 0; g < 3; ++g)
              acc[mt][g] = mfma3(ah, al, wh[g][ks], wl[g][ks], acc[mt][g]);
          }
        }
      }

      // partial handoff: waves (x,kh0)->0, (x,kh1)->1, (h,kh1)->2
      const int widx = (hside == 0) ? kh : (kh == 1 ? 2 : -1);
      if (widx >= 0) {
#pragma unroll
        for (int mt = 0; mt < 2; ++mt)
#pragma unroll
          for (int g = 0; g < 3; ++g)
#pragma unroll
            for (int r = 0; r < 4; ++r)
              part[widx][lane][mt * 12 + g * 4 + r] = acc[mt][g][r];
      }
    }
    __syncthreads();

    // ---- epilogue: combine partials, gate math, publish h ----
    if (act && hside == 1 && kh == 0) {
      const int wp = t & 1;
      unsigned short* oh = layer ? h2hi : h1hi;
      unsigned short* ol = layer ? h2lo : h1lo;
#pragma unroll
      for (int mt = 0; mt < 2; ++mt) {
#pragma unroll
        for (int r = 0; r < 4; ++r) {
          const int i0 = mt * 12 + r;
          float xr = part[0][lane][i0]     + part[1][lane][i0];
          float xz = part[0][lane][i0 + 4] + part[1][lane][i0 + 4];
          float xn = part[0][lane][i0 + 8] + part[1][lane][i0 + 8];
          float hr = acc[mt][0][r] + part[2][lane][i0];
          float hz = acc[mt][1][r] + part[2][lane][i0 + 4];
          float hn = acc[mt][2][r] + part[2][lane][i0 + 8];
          float rr = sigm(xr + hr + brz);
          float zz = sigm(xz + hz + bzz);
          float nn = tanh_f(xn + bin + rr * (hn + bhn));
          float h = (1.f - zz) * nn + zz * hown[mt][r];
          hown[mt][r] = h;
          const int row = (mhalf * 2 + mt) * 16 + kg * 4 + r;
          const size_t o = (size_t)wp * HP + (size_t)row * 512 + col;
          unsigned short hi = f2bf(h);
          oh[o] = hi;
          ol[o] = f2bf(h - bf2f(hi));
          if (layer == 1 && p == NPH - 1) h2fin[(size_t)row * 512 + col] = h;
        }
      }
    }

    // -------- grid barrier (round-1-proven release/acquire) --------
    tgt += NBLK;
    __syncthreads();
    if (tid == 0) {
      __hip_atomic_fetch_add(counter, 1u, __ATOMIC_RELEASE, __HIP_MEMORY_SCOPE_AGENT);
      while (__hip_atomic_load(counter, __ATOMIC_RELAXED, __HIP_MEMORY_SCOPE_AGENT) < tgt)
        __builtin_amdgcn_s_sleep(2);
      __threadfence();
    }
    __syncthreads();
  }
}

// ---------- epilogue: out = h2_last @ Wfc^T + bfc ----------
__global__ __launch_bounds__(256) void fc_kernel(const float* __restrict__ h2,
                                                 const float* __restrict__ Wfc,
                                                 const float* __restrict__ bfc,
                                                 float* __restrict__ out) {
  int gid = blockIdx.x * 256 + threadIdx.x;  // 0..16383
  int b = gid >> 7, o = gid & 127;
  const float* hp = h2 + (size_t)b * Hn;
  const float* wp = Wfc + (size_t)o * Hn;
  float acc = bfc[o];
#pragma unroll 8
  for (int k = 0; k < Hn; k += 4) {
    float4 h = *(const float4*)(hp + k);
    float4 w = *(const float4*)(wp + k);
    acc = fmaf(h.x, w.x, acc); acc = fmaf(h.y, w.y, acc);
    acc = fmaf(h.z, w.z, acc); acc = fmaf(h.w, w.w, acc);
  }
  out[gid] = acc;
}

// ---------- epilogue: out_cate = out @ Wfcc^T + bfcc ----------
__global__ __launch_bounds__(256) void fcc_kernel(const float* __restrict__ outv,
                                                  const float* __restrict__ Wfcc,
                                                  const float* __restrict__ bfcc,
                                                  float* __restrict__ oc) {
  int gid = blockIdx.x * 256 + threadIdx.x;  // 0..49151
  int b = gid / 384, g = gid - b * 384;
  const float* op = outv + (size_t)b * 128;
  const float* wp = Wfcc + (size_t)g * 128;
  float acc = bfcc[g];
#pragma unroll 8
  for (int k = 0; k < 128; k += 4) {
    float4 o4 = *(const float4*)(op + k);
    float4 w4 = *(const float4*)(wp + k);
    acc = fmaf(o4.x, w4.x, acc); acc = fmaf(o4.y, w4.y, acc);
    acc = fmaf(o4.z, w4.z, acc); acc = fmaf(o4.w, w4.w, acc);
  }
  oc[gid] = acc;
}

extern "C" void kernel_launch(void* const* d_in, const int* in_sizes, int n_in,
                              void* d_out, int out_size, void* d_ws, size_t ws_size,
                              hipStream_t stream) {
  (void)in_sizes; (void)n_in; (void)out_size; (void)ws_size;
  const float* x    = (const float*)d_in[0];
  const float* Wih0 = (const float*)d_in[1];
  const float* Whh0 = (const float*)d_in[2];
  const float* bih0 = (const float*)d_in[3];
  const float* bhh0 = (const float*)d_in[4];
  const float* Wih1 = (const float*)d_in[5];
  const float* Whh1 = (const float*)d_in[6];
  const float* bih1 = (const float*)d_in[7];
  const float* bhh1 = (const float*)d_in[8];
  const float* Wfc  = (const float*)d_in[9];
  const float* bfc  = (const float*)d_in[10];
  const float* Wfcc = (const float*)d_in[11];
  const float* bfcc = (const float*)d_in[12];

  char* w = (char*)d_ws;
  unsigned* counter = (unsigned*)w;
  unsigned short* h1hi = (unsigned short*)(w + 256);   // each: 2 parity * 65536 * 2B
  unsigned short* h1lo = h1hi + 2 * HP;
  unsigned short* h2hi = h1lo + 2 * HP;
  unsigned short* h2lo = h2hi + 2 * HP;
  float* h2fin = (float*)(w + 256 + (size_t)4 * 2 * HP * 2);
  const size_t total = 256 + (size_t)4 * 2 * HP * 2 + (size_t)HP * 4;  // ~1.3 MB

  hipMemsetAsync(d_ws, 0, total, stream);

  gru_fused<<<NBLK, 256, 0, stream>>>(x, Wih0, Whh0, bih0, bhh0,
                                      Wih1, Whh1, bih1, bhh1,
                                      counter, h1hi, h1lo, h2hi, h2lo, h2fin);

  float* out = (float*)d_out;
  fc_kernel<<<64, 256, 0, stream>>>(h2fin, Wfc, bfc, out);
  fcc_kernel<<<192, 256, 0, stream>>>(out, Wfcc, bfcc, out + 16384);
}

// Round 4
// 9985.970 us; speedup vs baseline: 4.9432x; 1.0857x over previous
//
#include <hip/hip_runtime.h>

#define Tn 512
#define Hn 512
#define HP 65536           // h elements per parity buffer (128*512)
#define NBLK 256
#define NPH 513

typedef __attribute__((ext_vector_type(8))) short s8v;     // 8 bf16 (MFMA A/B frag)
typedef __attribute__((ext_vector_type(4))) float f4v;     // MFMA acc
typedef __attribute__((ext_vector_type(4))) unsigned u4v;

__device__ __forceinline__ unsigned short f2bf(float f) {  // RNE
  unsigned u = __float_as_uint(f);
  u = u + 0x7fffu + ((u >> 16) & 1u);
  return (unsigned short)(u >> 16);
}
__device__ __forceinline__ float bf2f(unsigned short s) {
  return __uint_as_float(((unsigned)s) << 16);
}
__device__ __forceinline__ float sigm(float v) { return 1.f / (1.f + __expf(-v)); }
__device__ __forceinline__ float tanh_f(float v) {
  v = fminf(fmaxf(v, -15.f), 15.f);
  float e = __expf(2.f * v);
  return (e - 1.f) / (e + 1.f);
}
__device__ __forceinline__ f4v mfma3(s8v ah, s8v al, s8v wh, s8v wl, f4v c) {
  c = __builtin_amdgcn_mfma_f32_16x16x32_bf16(ah, wh, c, 0, 0, 0);
  c = __builtin_amdgcn_mfma_f32_16x16x32_bf16(al, wh, c, 0, 0, 0);
  c = __builtin_amdgcn_mfma_f32_16x16x32_bf16(ah, wl, c, 0, 0, 0);
  return c;
}

// ---------------- persistent fused 2-layer GRU ----------------
// 256 blocks, XCD-aware: bid = jg*8 + (layer*4 + mq)  ->  bid%8 constant per
// (layer,mq) group, so the 32 jg-blocks sharing an x/h row-slice share one XCD L2.
// Each block: 16 cols x 3 gates, rows [mq*32, mq*32+32).
// 4 waves: kh = wv&1 (K-half), hs = wv>>1 (0: input-side GEMM, 1: h-side GEMM).
// Weights: bf16 hi/lo fragments in VGPRs (192 VGPR), loaded once.
// Phase p: layer0 computes h1[p] (p<512); layer1 computes h2[p-1] (p>=1).
// x for step t+1 is register-prefetched during phase t (independent of barrier).
__global__ __launch_bounds__(256, 1) void gru_fused(
    const float* __restrict__ x,
    const float* __restrict__ Wih0, const float* __restrict__ Whh0,
    const float* __restrict__ bih0, const float* __restrict__ bhh0,
    const float* __restrict__ Wih1, const float* __restrict__ Whh1,
    const float* __restrict__ bih1, const float* __restrict__ bhh1,
    unsigned* __restrict__ counter,
    unsigned short* __restrict__ h1hi, unsigned short* __restrict__ h1lo,
    unsigned short* __restrict__ h2hi, unsigned short* __restrict__ h2lo,
    float* __restrict__ h2fin) {
  __shared__ float part[3][64][25];   // partial-acc handoff (stride 25: conflict-free)

  const int tid = threadIdx.x, lane = tid & 63, wv = tid >> 6;
  const int kh = wv & 1, hs = wv >> 1;
  const int colr = lane & 15, kg = lane >> 4;

  const int bid = blockIdx.x;
  const int mq = bid & 3;                  // row quarter (32 rows)
  const int layer = (bid >> 2) & 1;
  const int jg = bid >> 3;                 // 0..31 column group
  const int col = jg * 16 + colr;

  // ---- load weight fragments (this wave's matrix + K-half) ----
  // B-frag: lane holds W[col][k = kh*256 + ks*32 + kg*8 + e]
  const float* W = (layer == 0) ? (hs ? Whh0 : Wih0) : (hs ? Whh1 : Wih1);
  s8v wh[3][8], wl[3][8];
#pragma unroll
  for (int g = 0; g < 3; ++g) {
    const float* wrow = W + (size_t)(g * Hn + col) * Hn + kh * 256 + kg * 8;
#pragma unroll
    for (int ks = 0; ks < 8; ++ks) {
#pragma unroll
      for (int e = 0; e < 8; ++e) {
        float v = wrow[ks * 32 + e];
        unsigned short hi = f2bf(v);
        wh[g][ks][e] = (short)hi;
        wl[g][ks][e] = (short)f2bf(v - bf2f(hi));
      }
    }
  }

  // biases: only the epilogue wave (hs==1, kh==0)
  float brz = 0, bzz = 0, bin = 0, bhn = 0;
  if (hs == 1 && kh == 0) {
    const float* bi = layer ? bih1 : bih0;
    const float* bb = layer ? bhh1 : bhh0;
    brz = bi[col] + bb[col];
    bzz = bi[Hn + col] + bb[Hn + col];
    bin = bi[2 * Hn + col];
    bhn = bb[2 * Hn + col];
  }

  const bool is_xw = (layer == 0 && hs == 0);   // x-prefetching wave

  // x prefetch registers: 2 mt x 8 ks x 8 floats = 32 float4
  float4 xp[2][8][2];
  if (is_xw) {
#pragma unroll
    for (int mt = 0; mt < 2; ++mt) {
      const int rowA = (mq * 2 + mt) * 16 + colr;
      const float* xq = x + ((size_t)rowA * Tn) * 512 + kh * 256 + kg * 8;  // t = 0
#pragma unroll
      for (int ks = 0; ks < 8; ++ks) {
        xp[mt][ks][0] = *(const float4*)(xq + ks * 32);
        xp[mt][ks][1] = *(const float4*)(xq + ks * 32 + 4);
      }
    }
  }

  float hown[2][4] = {{0.f, 0.f, 0.f, 0.f}, {0.f, 0.f, 0.f, 0.f}};

  unsigned tgt = 0;
  for (int p = 0; p < NPH; ++p) {
    const bool act = (layer == 0) ? (p < Tn) : (p >= 1);
    const int t = (layer == 0) ? p : (p - 1);   // this block computes h[t]
    f4v acc[2][3];

    if (act) {
#pragma unroll
      for (int mt = 0; mt < 2; ++mt)
#pragma unroll
        for (int g = 0; g < 3; ++g) acc[mt][g] = (f4v){0.f, 0.f, 0.f, 0.f};

      if (is_xw) {
        // ---- x-input GEMM from prefetched registers; hi/lo by truncation ----
#pragma unroll
        for (int mt = 0; mt < 2; ++mt) {
#pragma unroll
          for (int ks = 0; ks < 8; ++ks) {
            float v[8];
            v[0] = xp[mt][ks][0].x; v[1] = xp[mt][ks][0].y;
            v[2] = xp[mt][ks][0].z; v[3] = xp[mt][ks][0].w;
            v[4] = xp[mt][ks][1].x; v[5] = xp[mt][ks][1].y;
            v[6] = xp[mt][ks][1].z; v[7] = xp[mt][ks][1].w;
            u4v au, lu;
#pragma unroll
            for (int q = 0; q < 4; ++q) {
              unsigned u0 = __float_as_uint(v[2 * q]);
              unsigned u1 = __float_as_uint(v[2 * q + 1]);
              unsigned m0 = u0 & 0xffff0000u, m1 = u1 & 0xffff0000u;
              au[q] = (u0 >> 16) | m1;
              float l0 = v[2 * q] - __uint_as_float(m0);
              float l1 = v[2 * q + 1] - __uint_as_float(m1);
              lu[q] = (__float_as_uint(l0) >> 16) | (__float_as_uint(l1) & 0xffff0000u);
            }
            s8v ah = __builtin_bit_cast(s8v, au);
            s8v al = __builtin_bit_cast(s8v, lu);
#pragma unroll
            for (int g = 0; g < 3; ++g)
              acc[mt][g] = mfma3(ah, al, wh[g][ks], wl[g][ks], acc[mt][g]);
          }
        }
        // ---- issue next-step x loads (overlap barrier + other waves' work) ----
        {
          const int tpre = (t + 1 < Tn) ? (t + 1) : (Tn - 1);
#pragma unroll
          for (int mt = 0; mt < 2; ++mt) {
            const int rowA = (mq * 2 + mt) * 16 + colr;
            const float* xq = x + ((size_t)rowA * Tn + tpre) * 512 + kh * 256 + kg * 8;
#pragma unroll
            for (int ks = 0; ks < 8; ++ks) {
              xp[mt][ks][0] = *(const float4*)(xq + ks * 32);
              xp[mt][ks][1] = *(const float4*)(xq + ks * 32 + 4);
            }
          }
        }
      } else {
        // ---- h-side GEMM (or layer1 input GEMM): batched loads, then MFMA ----
        const unsigned short *sh, *sl;
        int rp;
        if (layer == 0)   { sh = h1hi; sl = h1lo; rp = (t - 1) & 1; }  // h1[t-1]
        else if (hs == 0) { sh = h1hi; sl = h1lo; rp = t & 1; }        // h1[t]
        else              { sh = h2hi; sl = h2lo; rp = (t - 1) & 1; }  // h2[t-1]
        s8v AH[2][8], AL[2][8];
#pragma unroll
        for (int mt = 0; mt < 2; ++mt) {
          const int rowA = (mq * 2 + mt) * 16 + colr;
          const size_t base = (size_t)rp * HP + (size_t)rowA * 512 + kh * 256 + kg * 8;
#pragma unroll
          for (int ks = 0; ks < 8; ++ks) {
            AH[mt][ks] = *(const s8v*)(sh + base + ks * 32);
            AL[mt][ks] = *(const s8v*)(sl + base + ks * 32);
          }
        }
#pragma unroll
        for (int mt = 0; mt < 2; ++mt)
#pragma unroll
          for (int ks = 0; ks < 8; ++ks)
#pragma unroll
            for (int g = 0; g < 3; ++g)
              acc[mt][g] = mfma3(AH[mt][ks], AL[mt][ks], wh[g][ks], wl[g][ks], acc[mt][g]);
      }

      // partial handoff: waves (hs0,kh0)->0, (hs0,kh1)->1, (hs1,kh1)->2
      const int widx = (hs == 0) ? kh : (kh == 1 ? 2 : -1);
      if (widx >= 0) {
#pragma unroll
        for (int mt = 0; mt < 2; ++mt)
#pragma unroll
          for (int g = 0; g < 3; ++g)
#pragma unroll
            for (int r = 0; r < 4; ++r)
              part[widx][lane][mt * 12 + g * 4 + r] = acc[mt][g][r];
      }
    }
    __syncthreads();

    // ---- epilogue: combine partials, gate math, publish h ----
    if (act && hs == 1 && kh == 0) {
      const int wp = t & 1;
      unsigned short* oh = layer ? h2hi : h1hi;
      unsigned short* ol = layer ? h2lo : h1lo;
#pragma unroll
      for (int mt = 0; mt < 2; ++mt) {
#pragma unroll
        for (int r = 0; r < 4; ++r) {
          const int i0 = mt * 12 + r;
          float xr = part[0][lane][i0]     + part[1][lane][i0];
          float xz = part[0][lane][i0 + 4] + part[1][lane][i0 + 4];
          float xn = part[0][lane][i0 + 8] + part[1][lane][i0 + 8];
          float hr = acc[mt][0][r] + part[2][lane][i0];
          float hz = acc[mt][1][r] + part[2][lane][i0 + 4];
          float hn = acc[mt][2][r] + part[2][lane][i0 + 8];
          float rr = sigm(xr + hr + brz);
          float zz = sigm(xz + hz + bzz);
          float nn = tanh_f(xn + bin + rr * (hn + bhn));
          float h = (1.f - zz) * nn + zz * hown[mt][r];
          hown[mt][r] = h;
          const int row = (mq * 2 + mt) * 16 + kg * 4 + r;
          const size_t o = (size_t)wp * HP + (size_t)row * 512 + col;
          unsigned short hi = f2bf(h);
          oh[o] = hi;
          ol[o] = f2bf(h - bf2f(hi));
          if (layer == 1 && p == NPH - 1) h2fin[(size_t)row * 512 + col] = h;
        }
      }
    }

    // -------- grid barrier (release/acquire, device scope) --------
    tgt += NBLK;
    __syncthreads();
    if (tid == 0) {
      __hip_atomic_fetch_add(counter, 1u, __ATOMIC_RELEASE, __HIP_MEMORY_SCOPE_AGENT);
      while (__hip_atomic_load(counter, __ATOMIC_RELAXED, __HIP_MEMORY_SCOPE_AGENT) < tgt)
        __builtin_amdgcn_s_sleep(1);
      __threadfence();
    }
    __syncthreads();
  }
}

// ---------- epilogue: out = h2_last @ Wfc^T + bfc ----------
__global__ __launch_bounds__(256) void fc_kernel(const float* __restrict__ h2,
                                                 const float* __restrict__ Wfc,
                                                 const float* __restrict__ bfc,
                                                 float* __restrict__ out) {
  int gid = blockIdx.x * 256 + threadIdx.x;  // 0..16383
  int b = gid >> 7, o = gid & 127;
  const float* hp = h2 + (size_t)b * Hn;
  const float* wp = Wfc + (size_t)o * Hn;
  float acc = bfc[o];
#pragma unroll 8
  for (int k = 0; k < Hn; k += 4) {
    float4 h = *(const float4*)(hp + k);
    float4 w = *(const float4*)(wp + k);
    acc = fmaf(h.x, w.x, acc); acc = fmaf(h.y, w.y, acc);
    acc = fmaf(h.z, w.z, acc); acc = fmaf(h.w, w.w, acc);
  }
  out[gid] = acc;
}

// ---------- epilogue: out_cate = out @ Wfcc^T + bfcc ----------
__global__ __launch_bounds__(256) void fcc_kernel(const float* __restrict__ outv,
                                                  const float* __restrict__ Wfcc,
                                                  const float* __restrict__ bfcc,
                                                  float* __restrict__ oc) {
  int gid = blockIdx.x * 256 + threadIdx.x;  // 0..49151
  int b = gid / 384, g = gid - b * 384;
  const float* op = outv + (size_t)b * 128;
  const float* wp = Wfcc + (size_t)g * 128;
  float acc = bfcc[g];
#pragma unroll 8
  for (int k = 0; k < 128; k += 4) {
    float4 o4 = *(const float4*)(op + k);
    float4 w4 = *(const float4*)(wp + k);
    acc = fmaf(o4.x, w4.x, acc); acc = fmaf(o4.y, w4.y, acc);
    acc = fmaf(o4.z, w4.z, acc); acc = fmaf(o4.w, w4.w, acc);
  }
  oc[gid] = acc;
}

extern "C" void kernel_launch(void* const* d_in, const int* in_sizes, int n_in,
                              void* d_out, int out_size, void* d_ws, size_t ws_size,
                              hipStream_t stream) {
  (void)in_sizes; (void)n_in; (void)out_size; (void)ws_size;
  const float* x    = (const float*)d_in[0];
  const float* Wih0 = (const float*)d_in[1];
  const float* Whh0 = (const float*)d_in[2];
  const float* bih0 = (const float*)d_in[3];
  const float* bhh0 = (const float*)d_in[4];
  const float* Wih1 = (const float*)d_in[5];
  const float* Whh1 = (const float*)d_in[6];
  const float* bih1 = (const float*)d_in[7];
  const float* bhh1 = (const float*)d_in[8];
  const float* Wfc  = (const float*)d_in[9];
  const float* bfc  = (const float*)d_in[10];
  const float* Wfcc = (const float*)d_in[11];
  const float* bfcc = (const float*)d_in[12];

  char* w = (char*)d_ws;
  unsigned* counter = (unsigned*)w;
  unsigned short* h1hi = (unsigned short*)(w + 256);   // each: 2 parity * 65536 * 2B
  unsigned short* h1lo = h1hi + 2 * HP;
  unsigned short* h2hi = h1lo + 2 * HP;
  unsigned short* h2lo = h2hi + 2 * HP;
  float* h2fin = (float*)(w + 256 + (size_t)4 * 2 * HP * 2);
  const size_t total = 256 + (size_t)4 * 2 * HP * 2 + (size_t)HP * 4;  // ~1.3 MB

  hipMemsetAsync(d_ws, 0, total, stream);

  gru_fused<<<NBLK, 256, 0, stream>>>(x, Wih0, Whh0, bih0, bhh0,
                                      Wih1, Whh1, bih1, bhh1,
                                      counter, h1hi, h1lo, h2hi, h2lo, h2fin);

  float* out = (float*)d_out;
  fc_kernel<<<64, 256, 0, stream>>>(h2fin, Wfc, bfc, out);
  fcc_kernel<<<192, 256, 0, stream>>>(out, Wfcc, bfcc, out + 16384);
}